// Round 9
// baseline (14.824 us; speedup 1.0000x reference)
//
#include <hip/hip_runtime.h>

#define NT    10
#define NB    16
#define SEQ   512
#define KST   10
#define NCH   32              // chunks per sequence (one per lane in a 32-group)
#define CLEN  (SEQ / NCH)     // 16 intervals per chunk
#define GRP   50              // state-pairs per batch
#define NWAVE (NB * GRP)      // 800 independent waves
#define WPB   4               // waves per block
#define NBLK  (NWAVE / WPB)   // 200 blocks x 256 threads

// Wave = (batch b, states {2*grp, 2*grp+1}); lane (c, half) scans chunk c
// (16 intervals) for its state, producing the affine chunk-map
//   g_out = A*g_in + B ; I = C*g_in + D ; L = E*g_in + F.
// Maps compose associatively -> 5-step shfl_xor butterfly. With g0=0 the
// per-state totals are (D_full, F_full). No LDS, no __syncthreads anywhere.

__global__ __launch_bounds__(64 * WPB) void hawkes_scan(
    const float* __restrict__ times, const int* __restrict__ types,
    const float* __restrict__ Tptr,  const float* __restrict__ mu,
    const float* __restrict__ alpha, const float* __restrict__ beta,
    float* __restrict__ partial)
{
    const int gwid = blockIdx.x * WPB + (threadIdx.x >> 6);  // 0..799
    const int b    = gwid / GRP;
    const int grp  = gwid - b * GRP;
    const int lane = threadIdx.x & 63;
    const int half = lane >> 5;          // which of the 2 states
    const int c    = lane & 31;          // chunk index
    const int s    = grp * 2 + half;     // state 0..99
    const int a    = s / NT;             // source type
    const int m    = s - a * NT;         // target type

    const float Tv  = Tptr[0];
    const float al  = alpha[a * NT + m];
    const float be  = beta [a * NT + m];
    const float mum = (a == 0) ? mu[m] : 0.f;   // state (0,m) owns the mu[ty] term

    // preload this chunk's 16 times + 16 types into VGPRs (64B-aligned float4)
    const float4* tp = (const float4*)(times + b * SEQ + c * CLEN);
    const int4*   yp = (const int4*)  (types + b * SEQ + c * CLEN);
    const float4 T0 = tp[0], T1 = tp[1], T2 = tp[2], T3 = tp[3];
    const int4   Y0 = yp[0], Y1 = yp[1], Y2 = yp[2], Y3 = yp[3];

    // chunk-boundary time t[k0-1]: previous lane's last time (0 for c==0)
    float tprev = __shfl(T3.w, lane - 1, 64);
    if (c == 0) tprev = 0.f;

    float A = 1.f, B = 0.f, C = 0.f, D = 0.f, E = 0.f, F = 0.f;

#define STEP(TE, TY)                                                          \
    {                                                                         \
        const float h    = ((TE) - tprev) * (1.0f / KST);                     \
        tprev = (TE);                                                         \
        const float x    = be * h;                                            \
        const float e1   = __expf(-x);                                        \
        const float e10  = __expf(-10.f * x);                                 \
        const float gA   = (1.f - e10 * e1) * __builtin_amdgcn_rcpf(1.f - e1);\
        const float gB   = 11.f + x * (-55.f + 192.5f * x);                   \
        const float geom = (x > 1e-3f) ? gA : gB;                             \
        const float coef = al * geom * h;                                     \
        C = fmaf(coef, A, C);                                                 \
        D = fmaf(coef, B, D);                                                 \
        A *= e10;                                                             \
        B *= e10;                                                             \
        E = ((TY) == m) ? fmaf(al, A, E) : E;                                 \
        F = ((TY) == m) ? (F + fmaf(al, B, mum)) : F;                         \
        B += ((TY) == a) ? 1.f : 0.f;                                         \
    }

    STEP(T0.x, Y0.x) STEP(T0.y, Y0.y) STEP(T0.z, Y0.z) STEP(T0.w, Y0.w)
    STEP(T1.x, Y1.x) STEP(T1.y, Y1.y) STEP(T1.z, Y1.z) STEP(T1.w, Y1.w)
    STEP(T2.x, Y2.x) STEP(T2.y, Y2.y) STEP(T2.z, Y2.z) STEP(T2.w, Y2.w)
    STEP(T3.x, Y3.x) STEP(T3.y, Y3.y) STEP(T3.z, Y3.z) STEP(T3.w, Y3.w)
#undef STEP

    if (c == NCH - 1) {   // final interval (t_{S-1}, T]: quadrature only
        const float h    = (Tv - tprev) * (1.0f / KST);
        const float x    = be * h;
        const float e1   = __expf(-x);
        const float e10  = __expf(-10.f * x);
        const float gA   = (1.f - e10 * e1) * __builtin_amdgcn_rcpf(1.f - e1);
        const float gB   = 11.f + x * (-55.f + 192.5f * x);
        const float geom = (x > 1e-3f) ? gA : gB;
        const float coef = al * geom * h;
        C = fmaf(coef, A, C);
        D = fmaf(coef, B, D);
    }

    // butterfly composition over the 32 chunks (order: chunk 0 first)
    #pragma unroll
    for (int msk = 1; msk < 32; msk <<= 1) {
        const float pA = __shfl_xor(A, msk, 32);
        const float pB = __shfl_xor(B, msk, 32);
        const float pC = __shfl_xor(C, msk, 32);
        const float pD = __shfl_xor(D, msk, 32);
        const float pE = __shfl_xor(E, msk, 32);
        const float pF = __shfl_xor(F, msk, 32);
        const bool e = ((lane & msk) == 0);   // self is the earlier block
        const float Af = e ? A : pA, Bf = e ? B : pB, Cf = e ? C : pC,
                    Df = e ? D : pD, Ef = e ? E : pE, Ff = e ? F : pF;
        const float Ag = e ? pA : A, Bg = e ? pB : B, Cg = e ? pC : C,
                    Dg = e ? pD : D, Eg = e ? pE : E, Fg = e ? pF : F;
        A = Ag * Af;
        B = fmaf(Ag, Bf, Bg);
        C = fmaf(Cg, Af, Cf);
        D = Df + fmaf(Cg, Bf, Dg);
        E = fmaf(Eg, Af, Ef);
        F = Ff + fmaf(Eg, Bf, Fg);
    }

    const float v  = D - F;                 // per-state (integral - loglik), g0 = 0
    const float v2 = __shfl(v, lane ^ 32, 64);
    if (lane == 0) partial[gwid] = v + v2;
}

__global__ __launch_bounds__(64) void hawkes_sum(
    const float* __restrict__ partial, const float* __restrict__ mu,
    const float* __restrict__ Tptr, float* __restrict__ out)
{
    const int t = threadIdx.x;
    float S = 0.f;
    #pragma unroll
    for (int i = t; i < NWAVE; i += 64) S += partial[i];
    #pragma unroll
    for (int off = 32; off; off >>= 1) S += __shfl_down(S, off, 64);
    if (t == 0) {
        float mus = 0.f;
        #pragma unroll
        for (int i = 0; i < NT; ++i) mus += mu[i];
        // constant quadrature term: B * (STEPS+1) * sum(mu) * (T/STEPS)
        const float cst = (float)NB * (float)(KST + 1) * mus * Tptr[0] * (1.0f / KST);
        out[0] = S + cst;
    }
}

extern "C" void kernel_launch(void* const* d_in, const int* in_sizes, int n_in,
                              void* d_out, int out_size, void* d_ws, size_t ws_size,
                              hipStream_t stream) {
    const float* times = (const float*)d_in[0];
    const int*   types = (const int*)d_in[1];
    const float* T     = (const float*)d_in[2];
    const float* mu    = (const float*)d_in[3];
    const float* alpha = (const float*)d_in[4];
    const float* beta  = (const float*)d_in[5];
    float* partial = (float*)d_ws;     // 800 floats, fully overwritten every call
    float* out     = (float*)d_out;

    hawkes_scan<<<NBLK, 64 * WPB, 0, stream>>>(times, types, T, mu, alpha, beta, partial);
    hawkes_sum<<<1, 64, 0, stream>>>(partial, mu, T, out);
}

// Round 10
// 11.400 us; speedup vs baseline: 1.3003x; 1.3003x over previous
//
#include <hip/hip_runtime.h>

#define NT    10
#define NB    16
#define SEQ   512
#define KST   10
#define NCH   32              // chunks per sequence (one per lane in a 32-group)
#define CLEN  (SEQ / NCH)     // 16 intervals per chunk
#define GRP   50              // state-pairs per batch
#define NBLK  (NB * GRP)      // 800 blocks, 1 wave each

// Lane (c, s): scan chunk c (16 intervals) for state s=(a,m), producing the
// affine map over the chunk:  g_out = A*g_in + B ; I = C*g_in + D ; L = E*g_in + F.
// Maps compose associatively -> 5-step shfl_xor butterfly replaces the serial
// fold. With g0 = 0 the per-state totals are just (D_full, F_full).
// Block = 64 lanes = 32 chunks x 2 states. No LDS, no __syncthreads.
// 800 single-wave workgroups: each wave gets its own SIMD slot and retires
// independently (R9 showed packing 4 waves/block costs ~3 us in tail effects).

__global__ __launch_bounds__(64) void hawkes_scan(
    const float* __restrict__ times, const int* __restrict__ types,
    const float* __restrict__ Tptr,  const float* __restrict__ mu,
    const float* __restrict__ alpha, const float* __restrict__ beta,
    float* __restrict__ partial)
{
    const int blk  = blockIdx.x;
    const int b    = blk / GRP;
    const int grp  = blk - b * GRP;
    const int lane = threadIdx.x;
    const int half = lane >> 5;          // which of the 2 states
    const int c    = lane & 31;          // chunk index
    const int s    = grp * 2 + half;     // state 0..99
    const int a    = s / NT;             // source type
    const int m    = s - a * NT;         // target type

    const float al  = alpha[a * NT + m];
    const float be  = beta [a * NT + m];
    const float mum = (a == 0) ? mu[m] : 0.f;   // state (0,m) owns the mu[ty] term

    // preload this chunk's 16 times + 16 types into VGPRs (64B-aligned float4)
    const float4* tp = (const float4*)(times + b * SEQ + c * CLEN);
    const int4*   yp = (const int4*)  (types + b * SEQ + c * CLEN);
    const float4 T0 = tp[0], T1 = tp[1], T2 = tp[2], T3 = tp[3];
    const int4   Y0 = yp[0], Y1 = yp[1], Y2 = yp[2], Y3 = yp[3];

    // chunk-boundary time t[k0-1]: previous lane's last time (0 for c==0)
    float tprev = __shfl(T3.w, lane - 1, 64);
    if (c == 0) tprev = 0.f;

    float A = 1.f, B = 0.f, C = 0.f, D = 0.f, E = 0.f, F = 0.f;

#define STEP(TE, TY)                                                          \
    {                                                                         \
        const float h    = ((TE) - tprev) * (1.0f / KST);                     \
        tprev = (TE);                                                         \
        const float x    = be * h;                                            \
        const float e1   = __expf(-x);                                        \
        const float e10  = __expf(-10.f * x);                                 \
        const float gA   = (1.f - e10 * e1) * __builtin_amdgcn_rcpf(1.f - e1);\
        const float gB   = 11.f + x * (-55.f + 192.5f * x);                   \
        const float geom = (x > 1e-3f) ? gA : gB;                             \
        const float coef = al * geom * h;                                     \
        C = fmaf(coef, A, C);                                                 \
        D = fmaf(coef, B, D);                                                 \
        A *= e10;                                                             \
        B *= e10;                                                             \
        E = ((TY) == m) ? fmaf(al, A, E) : E;                                 \
        F = ((TY) == m) ? (F + fmaf(al, B, mum)) : F;                         \
        B += ((TY) == a) ? 1.f : 0.f;                                         \
    }

    STEP(T0.x, Y0.x) STEP(T0.y, Y0.y) STEP(T0.z, Y0.z) STEP(T0.w, Y0.w)
    STEP(T1.x, Y1.x) STEP(T1.y, Y1.y) STEP(T1.z, Y1.z) STEP(T1.w, Y1.w)
    STEP(T2.x, Y2.x) STEP(T2.y, Y2.y) STEP(T2.z, Y2.z) STEP(T2.w, Y2.w)
    STEP(T3.x, Y3.x) STEP(T3.y, Y3.y) STEP(T3.z, Y3.z) STEP(T3.w, Y3.w)
#undef STEP

    if (c == NCH - 1) {   // final interval (t_{S-1}, T]: quadrature only
        const float h    = (Tptr[0] - tprev) * (1.0f / KST);
        const float x    = be * h;
        const float e1   = __expf(-x);
        const float e10  = __expf(-10.f * x);
        const float gA   = (1.f - e10 * e1) * __builtin_amdgcn_rcpf(1.f - e1);
        const float gB   = 11.f + x * (-55.f + 192.5f * x);
        const float geom = (x > 1e-3f) ? gA : gB;
        const float coef = al * geom * h;
        C = fmaf(coef, A, C);
        D = fmaf(coef, B, D);
    }

    // butterfly composition over the 32 chunks (order: chunk 0 first)
    #pragma unroll
    for (int msk = 1; msk < 32; msk <<= 1) {
        const float pA = __shfl_xor(A, msk, 32);
        const float pB = __shfl_xor(B, msk, 32);
        const float pC = __shfl_xor(C, msk, 32);
        const float pD = __shfl_xor(D, msk, 32);
        const float pE = __shfl_xor(E, msk, 32);
        const float pF = __shfl_xor(F, msk, 32);
        const bool e = ((lane & msk) == 0);   // self is the earlier block
        const float Af = e ? A : pA, Bf = e ? B : pB, Cf = e ? C : pC,
                    Df = e ? D : pD, Ef = e ? E : pE, Ff = e ? F : pF;
        const float Ag = e ? pA : A, Bg = e ? pB : B, Cg = e ? pC : C,
                    Dg = e ? pD : D, Eg = e ? pE : E, Fg = e ? pF : F;
        A = Ag * Af;
        B = fmaf(Ag, Bf, Bg);
        C = fmaf(Cg, Af, Cf);
        D = Df + fmaf(Cg, Bf, Dg);
        E = fmaf(Eg, Af, Ef);
        F = Ff + fmaf(Eg, Bf, Fg);
    }

    const float v  = D - F;                 // per-state (integral - loglik), g0 = 0
    const float v2 = __shfl(v, lane ^ 32, 64);
    if (lane == 0) partial[blk] = v + v2;
}

__global__ __launch_bounds__(256) void hawkes_sum(
    const float* __restrict__ partial, const float* __restrict__ mu,
    const float* __restrict__ Tptr, float* __restrict__ out)
{
    const int t = threadIdx.x;
    float S = 0.f;
    for (int i = t; i < NBLK; i += 256) S += partial[i];
    for (int off = 32; off; off >>= 1) S += __shfl_down(S, off, 64);
    __shared__ float red[4];
    if ((t & 63) == 0) red[t >> 6] = S;
    __syncthreads();
    if (t == 0) {
        float mus = 0.f;
        #pragma unroll
        for (int i = 0; i < NT; ++i) mus += mu[i];
        // constant quadrature term: B * (STEPS+1) * sum(mu) * (T/STEPS)
        const float cst = (float)NB * (float)(KST + 1) * mus * Tptr[0] * (1.0f / KST);
        out[0] = red[0] + red[1] + red[2] + red[3] + cst;
    }
}

extern "C" void kernel_launch(void* const* d_in, const int* in_sizes, int n_in,
                              void* d_out, int out_size, void* d_ws, size_t ws_size,
                              hipStream_t stream) {
    const float* times = (const float*)d_in[0];
    const int*   types = (const int*)d_in[1];
    const float* T     = (const float*)d_in[2];
    const float* mu    = (const float*)d_in[3];
    const float* alpha = (const float*)d_in[4];
    const float* beta  = (const float*)d_in[5];
    float* partial = (float*)d_ws;     // 800 floats, fully overwritten every call
    float* out     = (float*)d_out;

    hawkes_scan<<<NBLK, 64, 0, stream>>>(times, types, T, mu, alpha, beta, partial);
    hawkes_sum<<<1, 256, 0, stream>>>(partial, mu, T, out);
}